// Round 8
// baseline (29.842 us; speedup 1.0000x reference)
//
#include <hip/hip_runtime.h>

namespace {

constexpr int kB  = 16384;  // rods
constexpr int kNV = 129;    // vertices per rod
constexpr int kNE = 128;    // edges per rod
constexpr int kWPB = 4;     // waves per block
constexpr int kRPW = 2;     // rods per wave

struct F3 { float x, y, z; };
struct Q4 { float w, x, y, z; };   // fp32 quaternion

__device__ __forceinline__ F3 crossf(F3 a, F3 b) {
    return { a.y*b.z - a.z*b.y,
             a.z*b.x - a.x*b.z,
             a.x*b.y - a.y*b.x };
}
__device__ __forceinline__ float dotf(F3 a, F3 b) { return a.x*b.x + a.y*b.y + a.z*b.z; }
__device__ __forceinline__ F3 subf(F3 a, F3 b) { return { a.x-b.x, a.y-b.y, a.z-b.z }; }
// matches ref _normalize: x / max(|x|, 1e-12)
__device__ __forceinline__ F3 nrmf(F3 a) {
    const float s = 1.0f / fmaxf(sqrtf(dotf(a, a)), 1e-12f);
    return { a.x*s, a.y*s, a.z*s };
}
// a (x) b : apply b first, then a
__device__ __forceinline__ Q4 qmul(Q4 a, Q4 b) {
    return { a.w*b.w - a.x*b.x - a.y*b.y - a.z*b.z,
             a.w*b.x + a.x*b.w + a.y*b.z - a.z*b.y,
             a.w*b.y - a.x*b.z + a.y*b.w + a.z*b.x,
             a.w*b.z + a.x*b.y - a.y*b.x + a.z*b.w };
}
// rotate x by unit quaternion q: x + 2w(v x x) + 2 v x (v x x)
__device__ __forceinline__ F3 qrot(Q4 q, F3 x) {
    const F3 v  = { q.x, q.y, q.z };
    const F3 t  = crossf(v, x);
    const F3 t2 = crossf(v, t);
    return { x.x + 2.0f*(q.w*t.x + t2.x),
             x.y + 2.0f*(q.w*t.y + t2.y),
             x.z + 2.0f*(q.w*t.z + t2.z) };
}
__device__ __forceinline__ Q4 shflup_q(Q4 a, int d) {
    Q4 r;
    r.w = __shfl_up(a.w, d, 64);
    r.x = __shfl_up(a.x, d, 64);
    r.y = __shfl_up(a.y, d, 64);
    r.z = __shfl_up(a.z, d, 64);
    return r;
}
// highest set bit index, m != 0
__device__ __forceinline__ int hbit(unsigned long long m) {
    return 63 - __builtin_clzll(m);
}

__device__ __forceinline__ void process_rod(
    const int lane, const int b,
    const float2 f0, const float2 f1, const float2 f2, const float2 Lp,
    const float* __restrict__ verts,
    const float* __restrict__ dinit,
    float* __restrict__ out)
{
    const int i0 = 2*lane, i1 = 2*lane + 1;

    const F3 vA = { f0.x, f0.y, f1.x };   // vertex 2l
    const F3 vB = { f1.y, f2.x, f2.y };   // vertex 2l+1

    // ---- wave-uniform reads -> scalar pipe ----
    const int bw = __builtin_amdgcn_readfirstlane(b);
    const float* Vu = verts + (size_t)bw * (kNV*3);
    const F3 vLast = { Vu[kNE*3+0], Vu[kNE*3+1], Vu[kNE*3+2] };   // vertex 128
    const F3 dvf   = { dinit[bw*3+0], dinit[bw*3+1], dinit[bw*3+2] };
    const F3 p0    = { Vu[0], Vu[1], Vu[2] };
    const F3 p1    = { Vu[3], Vu[4], Vu[5] };

    // ---- vC (vertex 2l+2) from neighbor lane; lane 63 takes vertex 128 ----
    F3 vC;
    vC.x = __shfl_down(vA.x, 1, 64);
    vC.y = __shfl_down(vA.y, 1, 64);
    vC.z = __shfl_down(vA.z, 1, 64);
    if (lane == 63) vC = vLast;

    // ---- fp64 edges (exact: fp32 promotes exactly, diffs fit 53 bits) ----
    const double eAdx = (double)vB.x - (double)vA.x;   // e_{2l}
    const double eAdy = (double)vB.y - (double)vA.y;
    const double eAdz = (double)vB.z - (double)vA.z;
    const double eBdx = (double)vC.x - (double)vB.x;   // e_{2l+1}
    const double eBdy = (double)vC.y - (double)vB.y;
    const double eBdz = (double)vC.z - (double)vB.z;
    // e_{2l-1} = previous lane's eB (bit-identical to loading vP and subtracting)
    const double ePdx = __shfl_up(eBdx, 1, 64);
    const double ePdy = __shfl_up(eBdy, 1, 64);
    const double ePdz = __shfl_up(eBdz, 1, 64);

    const F3 eAf = { (float)eAdx, (float)eAdy, (float)eAdz };
    const F3 eBf = { (float)eBdx, (float)eBdy, (float)eBdz };
    const F3 ePf = { (float)ePdx, (float)ePdy, (float)ePdz };

    // ---- u0 (identical in every lane), fp32 ----
    const F3 e0f = subf(p1, p0);
    const F3 u0  = nrmf(crossf(crossf(e0f, dvf), e0f));

    // ---- rest lengths: own pair + neighbor's high half ----
    const float lPf = __shfl_up(Lp.y, 1, 64);   // L[i0-1] (lane 0: unused)
    const double lA = (double)Lp.x;
    const double lB = (double)Lp.y;
    const double lP = (double)lPf;

    // ---- per-slot kb (fp64 denom, fp32 numerator), quaternion, activity ----
    F3  kb0 = {0.f, 0.f, 0.f};
    Q4  q0  = {1.f, 0.f, 0.f, 0.f};
    bool act0 = (lane == 0);          // index 0 is the u0/v0 anchor
    if (lane > 0) {
        const double denom = lP*lA + (ePdx*eAdx + ePdy*eAdy + ePdz*eAdz);
        const F3 c = crossf(ePf, eAf);
        const float rd = 2.0f / (float)denom;
        kb0 = { c.x*rd, c.y*rd, c.z*rd };
        const float mag = dotf(kb0, kb0);
        const float inv = 1.0f / (4.0f + mag);
        const float w   = sqrtf(4.0f * inv);
        if (1.0f - w > 1e-6f) {
            act0 = true;
            const float sp = sqrtf(mag * inv);                    // sinPhi
            const float as = sp / fmaxf(sqrtf(mag), 1e-12f);      // sinPhi/|kb|
            q0 = { w, kb0.x*as, kb0.y*as, kb0.z*as };
        }
    }

    F3  kb1;
    Q4  q1  = {1.f, 0.f, 0.f, 0.f};
    bool act1 = false;
    {
        const double denom = lA*lB + (eAdx*eBdx + eAdy*eBdy + eAdz*eBdz);
        const F3 c = crossf(eAf, eBf);
        const float rd = 2.0f / (float)denom;
        kb1 = { c.x*rd, c.y*rd, c.z*rd };
        const float mag = dotf(kb1, kb1);
        const float inv = 1.0f / (4.0f + mag);
        const float w   = sqrtf(4.0f * inv);
        if (1.0f - w > 1e-6f) {
            act1 = true;
            const float sp = sqrtf(mag * inv);
            const float as = sp / fmaxf(sqrtf(mag), 1e-12f);
            q1 = { w, kb1.x*as, kb1.y*as, kb1.z*as };
        }
    }

    // ---- Kogge-Stone inclusive scan of quaternion products (fp32) ----
    Q4 s = qmul(q1, q0);
    #pragma unroll
    for (int d = 1; d < 64; d <<= 1) {
        const Q4 t = shflup_q(s, d);
        if (lane >= d) s = qmul(s, t);
    }
    Q4 ex = shflup_q(s, 1);
    if (lane == 0) ex = {1.f, 0.f, 0.f, 0.f};
    const Q4 Qa = qmul(q0, ex);   // composed rotation up to index i0
    const Q4 Qb = s;              // composed rotation up to index i1

    // ---- last-active-index via ballot + clz ----
    const unsigned long long mask0 = __ballot(act0);   // bit l = act at slot 2l
    const unsigned long long mask1 = __ballot(act1);   // bit l = act at slot 2l+1
    const unsigned long long m0a = mask0 & (~0ull >> (63 - lane));          // bits 0..l (nonempty: bit0 set)
    const unsigned long long m1a = lane ? (mask1 & (~0ull >> (64 - lane))) : 0ull; // bits 0..l-1
    const int j0 = max(2*hbit(m0a), m1a ? 2*hbit(m1a)+1 : -1);
    const unsigned long long m1b = mask1 & (~0ull >> (63 - lane));          // bits 0..l
    const int j1 = max(2*hbit(m0a), m1b ? 2*hbit(m1b)+1 : -1);

    // ---- u_i = R(Q_i) u0 ----
    const F3 uA = qrot(Qa, u0);
    const F3 uB = qrot(Qb, u0);

    // ---- edges at j0/j1: almost always own eA/eB; rare wave-uniform gather ----
    F3 ej0 = eAf, ej1 = eBf;
    if (__any((j0 != i0) || (j1 != i1))) {
        const int s0 = j0 >> 1, s1 = j1 >> 1;
        const F3 a0 = { __shfl(eAf.x, s0, 64), __shfl(eAf.y, s0, 64), __shfl(eAf.z, s0, 64) };
        const F3 b0 = { __shfl(eBf.x, s0, 64), __shfl(eBf.y, s0, 64), __shfl(eBf.z, s0, 64) };
        const F3 a1 = { __shfl(eAf.x, s1, 64), __shfl(eAf.y, s1, 64), __shfl(eAf.z, s1, 64) };
        const F3 b1 = { __shfl(eBf.x, s1, 64), __shfl(eBf.y, s1, 64), __shfl(eBf.z, s1, 64) };
        ej0 = (j0 & 1) ? b0 : a0;
        ej1 = (j1 & 1) ? b1 : a1;
    }

    const F3 vvA = nrmf(crossf(ej0, uA));
    const F3 vvB = nrmf(crossf(ej1, uB));

    // ---- coalesced plain stores (NT regressed WRITE_SIZE by +14%) ----
    float* bu  = out + (size_t)b * (kNE*3);
    float* bv  = bu  + (size_t)kB * (kNE*3);
    float* kbo = bv  + (size_t)kB * (kNE*3);
    const int o = 6*lane;

    *(float2*)(bu  + o    ) = make_float2(uA.x, uA.y);
    *(float2*)(bu  + o + 2) = make_float2(uA.z, uB.x);
    *(float2*)(bu  + o + 4) = make_float2(uB.y, uB.z);

    *(float2*)(bv  + o    ) = make_float2(vvA.x, vvA.y);
    *(float2*)(bv  + o + 2) = make_float2(vvA.z, vvB.x);
    *(float2*)(bv  + o + 4) = make_float2(vvB.y, vvB.z);

    *(float2*)(kbo + o    ) = make_float2(kb0.x, kb0.y);
    *(float2*)(kbo + o + 2) = make_float2(kb0.z, kb1.x);
    *(float2*)(kbo + o + 4) = make_float2(kb1.y, kb1.z);
}

__global__ __launch_bounds__(256)
void rod_frames_scan_kernel(const float* __restrict__ verts,   // (B, 129, 3)
                            const float* __restrict__ dinit,   // (B, 3)
                            const float* __restrict__ restL,   // (B, 128)
                            float* __restrict__ out)           // [b_u | b_v | kb]
{
    const int wave = threadIdx.x >> 6;
    const int lane = threadIdx.x & 63;
    const int wid  = blockIdx.x * kWPB + wave;
    const int bA = kRPW*wid, bB = kRPW*wid + 1;

    // ---- prefetch BOTH rods' per-lane inputs up front: rod B's cold loads
    //      hide under rod A's scan/compute ----
    const float2* VA = (const float2*)(verts + (size_t)bA * (kNV*3));
    const float2* VB = (const float2*)(verts + (size_t)bB * (kNV*3));
    const float2 a0 = VA[3*lane + 0];
    const float2 a1 = VA[3*lane + 1];
    const float2 a2 = VA[3*lane + 2];
    const float2 b0 = VB[3*lane + 0];
    const float2 b1 = VB[3*lane + 1];
    const float2 b2 = VB[3*lane + 2];
    const float2 La = *(const float2*)(restL + (size_t)bA*kNE + 2*lane);
    const float2 Lb = *(const float2*)(restL + (size_t)bB*kNE + 2*lane);

    process_rod(lane, bA, a0, a1, a2, La, verts, dinit, out);
    process_rod(lane, bB, b0, b1, b2, Lb, verts, dinit, out);
}

} // namespace

extern "C" void kernel_launch(void* const* d_in, const int* in_sizes, int n_in,
                              void* d_out, int out_size, void* d_ws, size_t ws_size,
                              hipStream_t stream)
{
    const float* verts = (const float*)d_in[0];
    const float* dinit = (const float*)d_in[1];
    const float* restL = (const float*)d_in[2];
    float* out = (float*)d_out;

    dim3 grid(kB / (kWPB * kRPW));   // 2048 blocks x 4 waves x 2 rods = 16384 rods
    dim3 block(64 * kWPB);
    hipLaunchKernelGGL(rod_frames_scan_kernel, grid, block, 0, stream,
                       verts, dinit, restL, out);
}

// Round 9
// 29.500 us; speedup vs baseline: 1.0116x; 1.0116x over previous
//
#include <hip/hip_runtime.h>

namespace {

constexpr int kB  = 16384;  // rods
constexpr int kNV = 129;    // vertices per rod
constexpr int kNE = 128;    // edges per rod
constexpr int kRPB = 4;     // rods (= waves) per block

struct F3 { float x, y, z; };
struct Q4 { float w, x, y, z; };   // fp32 quaternion

__device__ __forceinline__ F3 crossf(F3 a, F3 b) {
    return { a.y*b.z - a.z*b.y,
             a.z*b.x - a.x*b.z,
             a.x*b.y - a.y*b.x };
}
__device__ __forceinline__ float dotf(F3 a, F3 b) { return a.x*b.x + a.y*b.y + a.z*b.z; }
__device__ __forceinline__ F3 subf(F3 a, F3 b) { return { a.x-b.x, a.y-b.y, a.z-b.z }; }
// matches ref _normalize: x / max(|x|, 1e-12)
__device__ __forceinline__ F3 nrmf(F3 a) {
    const float s = 1.0f / fmaxf(sqrtf(dotf(a, a)), 1e-12f);
    return { a.x*s, a.y*s, a.z*s };
}
// a (x) b : apply b first, then a
__device__ __forceinline__ Q4 qmul(Q4 a, Q4 b) {
    return { a.w*b.w - a.x*b.x - a.y*b.y - a.z*b.z,
             a.w*b.x + a.x*b.w + a.y*b.z - a.z*b.y,
             a.w*b.y - a.x*b.z + a.y*b.w + a.z*b.x,
             a.w*b.z + a.x*b.y - a.y*b.x + a.z*b.w };
}
// rotate x by unit quaternion q: x + 2w(v x x) + 2 v x (v x x)
__device__ __forceinline__ F3 qrot(Q4 q, F3 x) {
    const F3 v  = { q.x, q.y, q.z };
    const F3 t  = crossf(v, x);
    const F3 t2 = crossf(v, t);
    return { x.x + 2.0f*(q.w*t.x + t2.x),
             x.y + 2.0f*(q.w*t.y + t2.y),
             x.z + 2.0f*(q.w*t.z + t2.z) };
}
__device__ __forceinline__ Q4 shflup_q(Q4 a, int d) {
    Q4 r;
    r.w = __shfl_up(a.w, d, 64);
    r.x = __shfl_up(a.x, d, 64);
    r.y = __shfl_up(a.y, d, 64);
    r.z = __shfl_up(a.z, d, 64);
    return r;
}
// highest set bit index, m != 0
__device__ __forceinline__ int hbit(unsigned long long m) {
    return 63 - __builtin_clzll(m);
}

__global__ __launch_bounds__(256)
void rod_frames_scan_kernel(const float* __restrict__ verts,   // (B, 129, 3)
                            const float* __restrict__ dinit,   // (B, 3)
                            const float* __restrict__ restL,   // (B, 128)
                            float* __restrict__ out)           // [b_u | b_v | kb]
{
    const int wave = threadIdx.x >> 6;
    const int lane = threadIdx.x & 63;
    const int b = blockIdx.x * kRPB + wave;

    const int i0 = 2*lane, i1 = 2*lane + 1;

    // ---- per-lane vertex loads: ONLY own 2 vertices (3x float2, 8B aligned) ----
    const float2* V2 = (const float2*)(verts + (size_t)b * (kNV*3));
    const float2 f0 = V2[3*lane + 0];
    const float2 f1 = V2[3*lane + 1];
    const float2 f2 = V2[3*lane + 2];
    const F3 vA = { f0.x, f0.y, f1.x };   // vertex 2l
    const F3 vB = { f1.y, f2.x, f2.y };   // vertex 2l+1

    // ---- wave-uniform reads -> scalar pipe ----
    const int bw = __builtin_amdgcn_readfirstlane(b);
    const float* Vu = verts + (size_t)bw * (kNV*3);
    const F3 vLast = { Vu[kNE*3+0], Vu[kNE*3+1], Vu[kNE*3+2] };   // vertex 128
    const F3 dvf   = { dinit[bw*3+0], dinit[bw*3+1], dinit[bw*3+2] };
    const F3 p0    = { Vu[0], Vu[1], Vu[2] };
    const F3 p1    = { Vu[3], Vu[4], Vu[5] };

    // ---- vC (vertex 2l+2) from neighbor lane; lane 63 takes vertex 128 ----
    F3 vC;
    vC.x = __shfl_down(vA.x, 1, 64);
    vC.y = __shfl_down(vA.y, 1, 64);
    vC.z = __shfl_down(vA.z, 1, 64);
    if (lane == 63) vC = vLast;

    // ---- fp64 edges (exact: fp32 promotes exactly, diffs fit 53 bits) ----
    const double eAdx = (double)vB.x - (double)vA.x;   // e_{2l}
    const double eAdy = (double)vB.y - (double)vA.y;
    const double eAdz = (double)vB.z - (double)vA.z;
    const double eBdx = (double)vC.x - (double)vB.x;   // e_{2l+1}
    const double eBdy = (double)vC.y - (double)vB.y;
    const double eBdz = (double)vC.z - (double)vB.z;
    // e_{2l-1} = previous lane's eB (bit-identical to loading vP and subtracting)
    const double ePdx = __shfl_up(eBdx, 1, 64);
    const double ePdy = __shfl_up(eBdy, 1, 64);
    const double ePdz = __shfl_up(eBdz, 1, 64);

    const F3 eAf = { (float)eAdx, (float)eAdy, (float)eAdz };
    const F3 eBf = { (float)eBdx, (float)eBdy, (float)eBdz };
    const F3 ePf = { (float)ePdx, (float)ePdy, (float)ePdz };

    // ---- u0 (identical in every lane), fp32 ----
    const F3 e0f = subf(p1, p0);
    const F3 u0  = nrmf(crossf(crossf(e0f, dvf), e0f));

    // ---- rest lengths: own pair + neighbor's high half ----
    const float2 Lp = *(const float2*)(restL + (size_t)b*kNE + i0);
    const float lPf = __shfl_up(Lp.y, 1, 64);   // L[i0-1] (lane 0: unused)
    const double lA = (double)Lp.x;
    const double lB = (double)Lp.y;
    const double lP = (double)lPf;

    // ---- per-slot kb (fp64 denom, fp32 numerator), quaternion, activity ----
    F3  kb0 = {0.f, 0.f, 0.f};
    Q4  q0  = {1.f, 0.f, 0.f, 0.f};
    bool act0 = (lane == 0);          // index 0 is the u0/v0 anchor
    if (lane > 0) {
        const double denom = lP*lA + (ePdx*eAdx + ePdy*eAdy + ePdz*eAdz);
        const F3 c = crossf(ePf, eAf);
        const float rd = 2.0f / (float)denom;
        kb0 = { c.x*rd, c.y*rd, c.z*rd };
        const float mag = dotf(kb0, kb0);
        const float inv = 1.0f / (4.0f + mag);
        const float w   = sqrtf(4.0f * inv);
        if (1.0f - w > 1e-6f) {
            act0 = true;
            const float sp = sqrtf(mag * inv);                    // sinPhi
            const float as = sp / fmaxf(sqrtf(mag), 1e-12f);      // sinPhi/|kb|
            q0 = { w, kb0.x*as, kb0.y*as, kb0.z*as };
        }
    }

    F3  kb1;
    Q4  q1  = {1.f, 0.f, 0.f, 0.f};
    bool act1 = false;
    {
        const double denom = lA*lB + (eAdx*eBdx + eAdy*eBdy + eAdz*eBdz);
        const F3 c = crossf(eAf, eBf);
        const float rd = 2.0f / (float)denom;
        kb1 = { c.x*rd, c.y*rd, c.z*rd };
        const float mag = dotf(kb1, kb1);
        const float inv = 1.0f / (4.0f + mag);
        const float w   = sqrtf(4.0f * inv);
        if (1.0f - w > 1e-6f) {
            act1 = true;
            const float sp = sqrtf(mag * inv);
            const float as = sp / fmaxf(sqrtf(mag), 1e-12f);
            q1 = { w, kb1.x*as, kb1.y*as, kb1.z*as };
        }
    }

    // ---- Kogge-Stone inclusive scan of quaternion products (fp32) ----
    Q4 s = qmul(q1, q0);
    #pragma unroll
    for (int d = 1; d < 64; d <<= 1) {
        const Q4 t = shflup_q(s, d);
        if (lane >= d) s = qmul(s, t);
    }
    Q4 ex = shflup_q(s, 1);
    if (lane == 0) ex = {1.f, 0.f, 0.f, 0.f};
    const Q4 Qa = qmul(q0, ex);   // composed rotation up to index i0
    const Q4 Qb = s;              // composed rotation up to index i1

    // ---- last-active-index via ballot + clz ----
    const unsigned long long mask0 = __ballot(act0);   // bit l = act at slot 2l
    const unsigned long long mask1 = __ballot(act1);   // bit l = act at slot 2l+1
    const unsigned long long m0a = mask0 & (~0ull >> (63 - lane));          // bits 0..l (nonempty: bit0 set)
    const unsigned long long m1a = lane ? (mask1 & (~0ull >> (64 - lane))) : 0ull; // bits 0..l-1
    const int j0 = max(2*hbit(m0a), m1a ? 2*hbit(m1a)+1 : -1);
    const unsigned long long m1b = mask1 & (~0ull >> (63 - lane));          // bits 0..l
    const int j1 = max(2*hbit(m0a), m1b ? 2*hbit(m1b)+1 : -1);

    // ---- u_i = R(Q_i) u0 ----
    const F3 uA = qrot(Qa, u0);
    const F3 uB = qrot(Qb, u0);

    // ---- edges at j0/j1: almost always own eA/eB; rare wave-uniform gather ----
    F3 ej0 = eAf, ej1 = eBf;
    if (__any((j0 != i0) || (j1 != i1))) {
        const int s0 = j0 >> 1, s1 = j1 >> 1;
        const F3 a0 = { __shfl(eAf.x, s0, 64), __shfl(eAf.y, s0, 64), __shfl(eAf.z, s0, 64) };
        const F3 b0 = { __shfl(eBf.x, s0, 64), __shfl(eBf.y, s0, 64), __shfl(eBf.z, s0, 64) };
        const F3 a1 = { __shfl(eAf.x, s1, 64), __shfl(eAf.y, s1, 64), __shfl(eAf.z, s1, 64) };
        const F3 b1 = { __shfl(eBf.x, s1, 64), __shfl(eBf.y, s1, 64), __shfl(eBf.z, s1, 64) };
        ej0 = (j0 & 1) ? b0 : a0;
        ej1 = (j1 & 1) ? b1 : a1;
    }

    const F3 vvA = nrmf(crossf(ej0, uA));
    const F3 vvB = nrmf(crossf(ej1, uB));

    // ---- coalesced plain stores (NT stores inflated WRITE_SIZE +14%) ----
    float* bu  = out + (size_t)b * (kNE*3);
    float* bv  = bu  + (size_t)kB * (kNE*3);
    float* kbo = bv  + (size_t)kB * (kNE*3);
    const int o = 6*lane;

    *(float2*)(bu  + o    ) = make_float2(uA.x, uA.y);
    *(float2*)(bu  + o + 2) = make_float2(uA.z, uB.x);
    *(float2*)(bu  + o + 4) = make_float2(uB.y, uB.z);

    *(float2*)(bv  + o    ) = make_float2(vvA.x, vvA.y);
    *(float2*)(bv  + o + 2) = make_float2(vvA.z, vvB.x);
    *(float2*)(bv  + o + 4) = make_float2(vvB.y, vvB.z);

    *(float2*)(kbo + o    ) = make_float2(kb0.x, kb0.y);
    *(float2*)(kbo + o + 2) = make_float2(kb0.z, kb1.x);
    *(float2*)(kbo + o + 4) = make_float2(kb1.y, kb1.z);
}

} // namespace

extern "C" void kernel_launch(void* const* d_in, const int* in_sizes, int n_in,
                              void* d_out, int out_size, void* d_ws, size_t ws_size,
                              hipStream_t stream)
{
    const float* verts = (const float*)d_in[0];
    const float* dinit = (const float*)d_in[1];
    const float* restL = (const float*)d_in[2];
    float* out = (float*)d_out;

    dim3 grid(kB / kRPB);
    dim3 block(64 * kRPB);
    hipLaunchKernelGGL(rod_frames_scan_kernel, grid, block, 0, stream,
                       verts, dinit, restL, out);
}

// Round 10
// 27.376 us; speedup vs baseline: 1.0901x; 1.0776x over previous
//
#include <hip/hip_runtime.h>

namespace {

constexpr int kB  = 16384;  // rods
constexpr int kNV = 129;    // vertices per rod
constexpr int kNE = 128;    // edges per rod
constexpr int kRPB = 4;     // rods (= waves) per block

typedef float v2f __attribute__((ext_vector_type(2)));   // NT-store-compatible

struct F3 { float x, y, z; };
struct Q4 { float w, x, y, z; };   // fp32 quaternion

// ---- DPP whole-wave shifts (CDNA keeps gfx9 wave_shr/shl) ----
// wave_shr:1 (0x138): lane i <- lane i-1  (== __shfl_up(x,1))
// wave_shl:1 (0x130): lane i <- lane i+1  (== __shfl_down(x,1))
__device__ __forceinline__ float dpp_up1(float x) {
    const int i = __float_as_int(x);
    return __int_as_float(__builtin_amdgcn_update_dpp(i, i, 0x138, 0xf, 0xf, false));
}
__device__ __forceinline__ float dpp_dn1(float x) {
    const int i = __float_as_int(x);
    return __int_as_float(__builtin_amdgcn_update_dpp(i, i, 0x130, 0xf, 0xf, false));
}
__device__ __forceinline__ double dpp_up1_d(double x) {
    const long long v = __double_as_longlong(x);
    const int lo = (int)(v & 0xffffffffll);
    const int hi = (int)(v >> 32);
    const int rlo = __builtin_amdgcn_update_dpp(lo, lo, 0x138, 0xf, 0xf, false);
    const int rhi = __builtin_amdgcn_update_dpp(hi, hi, 0x138, 0xf, 0xf, false);
    return __longlong_as_double(((long long)(unsigned int)rlo) | (((long long)rhi) << 32));
}

__device__ __forceinline__ F3 crossf(F3 a, F3 b) {
    return { a.y*b.z - a.z*b.y,
             a.z*b.x - a.x*b.z,
             a.x*b.y - a.y*b.x };
}
__device__ __forceinline__ float dotf(F3 a, F3 b) { return a.x*b.x + a.y*b.y + a.z*b.z; }
__device__ __forceinline__ F3 subf(F3 a, F3 b) { return { a.x-b.x, a.y-b.y, a.z-b.z }; }
// matches ref _normalize: x / max(|x|, 1e-12)
__device__ __forceinline__ F3 nrmf(F3 a) {
    const float s = 1.0f / fmaxf(sqrtf(dotf(a, a)), 1e-12f);
    return { a.x*s, a.y*s, a.z*s };
}
// a (x) b : apply b first, then a
__device__ __forceinline__ Q4 qmul(Q4 a, Q4 b) {
    return { a.w*b.w - a.x*b.x - a.y*b.y - a.z*b.z,
             a.w*b.x + a.x*b.w + a.y*b.z - a.z*b.y,
             a.w*b.y - a.x*b.z + a.y*b.w + a.z*b.x,
             a.w*b.z + a.x*b.y - a.y*b.x + a.z*b.w };
}
// rotate x by unit quaternion q: x + 2w(v x x) + 2 v x (v x x)
__device__ __forceinline__ F3 qrot(Q4 q, F3 x) {
    const F3 v  = { q.x, q.y, q.z };
    const F3 t  = crossf(v, x);
    const F3 t2 = crossf(v, t);
    return { x.x + 2.0f*(q.w*t.x + t2.x),
             x.y + 2.0f*(q.w*t.y + t2.y),
             x.z + 2.0f*(q.w*t.z + t2.z) };
}
__device__ __forceinline__ Q4 shflup_q(Q4 a, int d) {
    Q4 r;
    r.w = __shfl_up(a.w, d, 64);
    r.x = __shfl_up(a.x, d, 64);
    r.y = __shfl_up(a.y, d, 64);
    r.z = __shfl_up(a.z, d, 64);
    return r;
}
__device__ __forceinline__ Q4 dppup_q(Q4 a) {
    return { dpp_up1(a.w), dpp_up1(a.x), dpp_up1(a.y), dpp_up1(a.z) };
}
// highest set bit index, m != 0
__device__ __forceinline__ int hbit(unsigned long long m) {
    return 63 - __builtin_clzll(m);
}
__device__ __forceinline__ void nts2(float* p, float a, float bq) {
    v2f v = { a, bq };
    __builtin_nontemporal_store(v, (v2f*)p);
}

__global__ __launch_bounds__(256)
void rod_frames_scan_kernel(const float* __restrict__ verts,   // (B, 129, 3)
                            const float* __restrict__ dinit,   // (B, 3)
                            const float* __restrict__ restL,   // (B, 128)
                            float* __restrict__ out)           // [b_u | b_v | kb]
{
    const int wave = threadIdx.x >> 6;
    const int lane = threadIdx.x & 63;
    const int b = blockIdx.x * kRPB + wave;

    const int i0 = 2*lane, i1 = 2*lane + 1;

    // ---- per-lane vertex loads: ONLY own 2 vertices (3x float2, 8B aligned) ----
    const float2* V2 = (const float2*)(verts + (size_t)b * (kNV*3));
    const float2 f0 = V2[3*lane + 0];
    const float2 f1 = V2[3*lane + 1];
    const float2 f2 = V2[3*lane + 2];
    const F3 vA = { f0.x, f0.y, f1.x };   // vertex 2l
    const F3 vB = { f1.y, f2.x, f2.y };   // vertex 2l+1

    // ---- wave-uniform reads -> scalar pipe ----
    const int bw = __builtin_amdgcn_readfirstlane(b);
    const float* Vu = verts + (size_t)bw * (kNV*3);
    const F3 vLast = { Vu[kNE*3+0], Vu[kNE*3+1], Vu[kNE*3+2] };   // vertex 128
    const F3 dvf   = { dinit[bw*3+0], dinit[bw*3+1], dinit[bw*3+2] };
    const F3 p0    = { Vu[0], Vu[1], Vu[2] };
    const F3 p1    = { Vu[3], Vu[4], Vu[5] };

    // ---- vC (vertex 2l+2) from neighbor lane via DPP; lane 63 takes vertex 128 ----
    F3 vC = { dpp_dn1(vA.x), dpp_dn1(vA.y), dpp_dn1(vA.z) };
    if (lane == 63) vC = vLast;

    // ---- fp64 edges (exact: fp32 promotes exactly, diffs fit 53 bits) ----
    const double eAdx = (double)vB.x - (double)vA.x;   // e_{2l}
    const double eAdy = (double)vB.y - (double)vA.y;
    const double eAdz = (double)vB.z - (double)vA.z;
    const double eBdx = (double)vC.x - (double)vB.x;   // e_{2l+1}
    const double eBdy = (double)vC.y - (double)vB.y;
    const double eBdz = (double)vC.z - (double)vB.z;
    // e_{2l-1} = previous lane's eB via DPP (bit-identical; lane 0 unused)
    const double ePdx = dpp_up1_d(eBdx);
    const double ePdy = dpp_up1_d(eBdy);
    const double ePdz = dpp_up1_d(eBdz);

    const F3 eAf = { (float)eAdx, (float)eAdy, (float)eAdz };
    const F3 eBf = { (float)eBdx, (float)eBdy, (float)eBdz };
    const F3 ePf = { (float)ePdx, (float)ePdy, (float)ePdz };

    // ---- u0 (identical in every lane), fp32 ----
    const F3 e0f = subf(p1, p0);
    const F3 u0  = nrmf(crossf(crossf(e0f, dvf), e0f));

    // ---- rest lengths: own pair + neighbor's high half via DPP ----
    const float2 Lp = *(const float2*)(restL + (size_t)b*kNE + i0);
    const float lPf = dpp_up1(Lp.y);   // L[i0-1] (lane 0: unused)
    const double lA = (double)Lp.x;
    const double lB = (double)Lp.y;
    const double lP = (double)lPf;

    // ---- per-slot kb (fp64 denom, fp32 numerator), quaternion, activity ----
    F3  kb0 = {0.f, 0.f, 0.f};
    Q4  q0  = {1.f, 0.f, 0.f, 0.f};
    bool act0 = (lane == 0);          // index 0 is the u0/v0 anchor
    if (lane > 0) {
        const double denom = lP*lA + (ePdx*eAdx + ePdy*eAdy + ePdz*eAdz);
        const F3 c = crossf(ePf, eAf);
        const float rd = 2.0f / (float)denom;
        kb0 = { c.x*rd, c.y*rd, c.z*rd };
        const float mag = dotf(kb0, kb0);
        const float inv = 1.0f / (4.0f + mag);
        const float w   = sqrtf(4.0f * inv);
        if (1.0f - w > 1e-6f) {
            act0 = true;
            const float sp = sqrtf(mag * inv);                    // sinPhi
            const float as = sp / fmaxf(sqrtf(mag), 1e-12f);      // sinPhi/|kb|
            q0 = { w, kb0.x*as, kb0.y*as, kb0.z*as };
        }
    }

    F3  kb1;
    Q4  q1  = {1.f, 0.f, 0.f, 0.f};
    bool act1 = false;
    {
        const double denom = lA*lB + (eAdx*eBdx + eAdy*eBdy + eAdz*eBdz);
        const F3 c = crossf(eAf, eBf);
        const float rd = 2.0f / (float)denom;
        kb1 = { c.x*rd, c.y*rd, c.z*rd };
        const float mag = dotf(kb1, kb1);
        const float inv = 1.0f / (4.0f + mag);
        const float w   = sqrtf(4.0f * inv);
        if (1.0f - w > 1e-6f) {
            act1 = true;
            const float sp = sqrtf(mag * inv);
            const float as = sp / fmaxf(sqrtf(mag), 1e-12f);
            q1 = { w, kb1.x*as, kb1.y*as, kb1.z*as };
        }
    }

    // ---- Kogge-Stone inclusive scan of quaternion products (fp32) ----
    // level d=1 via DPP (VALU), d=2..32 via ds_bpermute shuffles
    Q4 s = qmul(q1, q0);
    {
        const Q4 t = dppup_q(s);
        if (lane >= 1) s = qmul(s, t);
    }
    #pragma unroll
    for (int d = 2; d < 64; d <<= 1) {
        const Q4 t = shflup_q(s, d);
        if (lane >= d) s = qmul(s, t);
    }
    Q4 ex = dppup_q(s);
    if (lane == 0) ex = {1.f, 0.f, 0.f, 0.f};
    const Q4 Qa = qmul(q0, ex);   // composed rotation up to index i0
    const Q4 Qb = s;              // composed rotation up to index i1

    // ---- last-active-index via ballot + clz ----
    const unsigned long long mask0 = __ballot(act0);   // bit l = act at slot 2l
    const unsigned long long mask1 = __ballot(act1);   // bit l = act at slot 2l+1
    const unsigned long long m0a = mask0 & (~0ull >> (63 - lane));          // bits 0..l (nonempty: bit0 set)
    const unsigned long long m1a = lane ? (mask1 & (~0ull >> (64 - lane))) : 0ull; // bits 0..l-1
    const int j0 = max(2*hbit(m0a), m1a ? 2*hbit(m1a)+1 : -1);
    const unsigned long long m1b = mask1 & (~0ull >> (63 - lane));          // bits 0..l
    const int j1 = max(2*hbit(m0a), m1b ? 2*hbit(m1b)+1 : -1);

    // ---- u_i = R(Q_i) u0 ----
    const F3 uA = qrot(Qa, u0);
    const F3 uB = qrot(Qb, u0);

    // ---- edges at j0/j1: almost always own eA/eB; rare wave-uniform gather ----
    F3 ej0 = eAf, ej1 = eBf;
    if (__any((j0 != i0) || (j1 != i1))) {
        const int s0 = j0 >> 1, s1 = j1 >> 1;
        const F3 a0 = { __shfl(eAf.x, s0, 64), __shfl(eAf.y, s0, 64), __shfl(eAf.z, s0, 64) };
        const F3 b0 = { __shfl(eBf.x, s0, 64), __shfl(eBf.y, s0, 64), __shfl(eBf.z, s0, 64) };
        const F3 a1 = { __shfl(eAf.x, s1, 64), __shfl(eAf.y, s1, 64), __shfl(eAf.z, s1, 64) };
        const F3 b1 = { __shfl(eBf.x, s1, 64), __shfl(eBf.y, s1, 64), __shfl(eBf.z, s1, 64) };
        ej0 = (j0 & 1) ? b0 : a0;
        ej1 = (j1 & 1) ? b1 : a1;
    }

    const F3 vvA = nrmf(crossf(ej0, uA));
    const F3 vvB = nrmf(crossf(ej1, uB));

    // ---- coalesced NT stores (empirically -2.3us vs plain despite +10MB WRITE_SIZE:
    //      write-once stream bypasses L2/L3, preserving them for inputs) ----
    float* bu  = out + (size_t)b * (kNE*3);
    float* bv  = bu  + (size_t)kB * (kNE*3);
    float* kbo = bv  + (size_t)kB * (kNE*3);
    const int o = 6*lane;

    nts2(bu + o    , uA.x, uA.y);
    nts2(bu + o + 2, uA.z, uB.x);
    nts2(bu + o + 4, uB.y, uB.z);

    nts2(bv + o    , vvA.x, vvA.y);
    nts2(bv + o + 2, vvA.z, vvB.x);
    nts2(bv + o + 4, vvB.y, vvB.z);

    nts2(kbo + o    , kb0.x, kb0.y);
    nts2(kbo + o + 2, kb0.z, kb1.x);
    nts2(kbo + o + 4, kb1.y, kb1.z);
}

} // namespace

extern "C" void kernel_launch(void* const* d_in, const int* in_sizes, int n_in,
                              void* d_out, int out_size, void* d_ws, size_t ws_size,
                              hipStream_t stream)
{
    const float* verts = (const float*)d_in[0];
    const float* dinit = (const float*)d_in[1];
    const float* restL = (const float*)d_in[2];
    float* out = (float*)d_out;

    dim3 grid(kB / kRPB);
    dim3 block(64 * kRPB);
    hipLaunchKernelGGL(rod_frames_scan_kernel, grid, block, 0, stream,
                       verts, dinit, restL, out);
}